// Round 15
// baseline (178.813 us; speedup 1.0000x reference)
//
#include <hip/hip_runtime.h>
#include <hip/hip_fp16.h>
#include <math.h>

#define EMB 128
#define NGRAPH 512
#define MAXBUCK 800          // max buckets (N up to 51200 @ 64 nodes/bucket)
#define BCAP 1536            // per-bucket edge capacity
#define CHUNK 2048           // edges per bscatter block
#define NCNT 120             // bcount blocks

typedef _Float16 f16_t;
typedef _Float16 f16x8 __attribute__((ext_vector_type(8)));
typedef float f32x4 __attribute__((ext_vector_type(4)));
typedef float f32x2 __attribute__((ext_vector_type(2)));

__device__ __forceinline__ float leaky(float v){ return v > 0.f ? v : 0.2f*v; }
__device__ __forceinline__ float ftanh(float x){
    float u = __expf(2.f*x);
    return 1.f - 2.f*__builtin_amdgcn_rcpf(u + 1.f);
}
__device__ __forceinline__ float frcp(float x){ return __builtin_amdgcn_rcpf(x); }

// ---------- fused independent prep ----------
__global__ __launch_bounds__(256) void k_misc(const float* W0, const float* as0, const float* ad0,
                                              float* c_sd, const float* W1, f16_t* W1t,
                                              const float* Wout, int OUT, f16_t* WoutT,
                                              const int* dst, int E, int nbuck, int* bcnt_part,
                                              float* zbuf, int zfloat4,
                                              const int* batch, int N, int* gstart){
    __shared__ f16_t lt[64*68];
    __shared__ float s1[128], s2[128];
    __shared__ int h[MAXBUCK];
    int b = blockIdx.x;
    int t = threadIdx.x;
    if(b < 272){
        int n0 = (b%68)*64, k0 = (b/68)*64;
        #pragma unroll
        for(int j=0;j<16;j++){
            int k_l = (t>>6)*16 + j;
            int n_l = t&63;
            int n = n0+n_l;
            float v = (n < OUT) ? Wout[(size_t)(k0+k_l)*OUT + n] : 0.f;
            lt[n_l*68 + k_l] = (f16_t)v;
        }
        __syncthreads();
        #pragma unroll
        for(int j=0;j<16;j++){
            int n_l = (t>>6)*16 + j;
            int k_l = t&63;
            WoutT[(size_t)(n0+n_l)*256 + k0 + k_l] = lt[n_l*68 + k_l];
        }
    } else if(b < 336){
        int idx = (b-272)*256 + t;
        int n = idx>>7, k = idx&127;
        W1t[n*128+k] = (f16_t)W1[k*128+n];
    } else if(b == 336){
        if(t<128){ float w = W0[t]; s1[t]=w*as0[t]; s2[t]=w*ad0[t]; }
        __syncthreads();
        for(int off=64; off>0; off>>=1){
            if(t<off){ s1[t]+=s1[t+off]; s2[t]+=s2[t+off]; }
            __syncthreads();
        }
        if(t==0){ c_sd[0]=s1[0]; c_sd[1]=s2[0]; }
    } else if(b < 457){
        int bb = b-337;
        for(int j=t;j<MAXBUCK;j+=256) h[j]=0;
        __syncthreads();
        int stride = NCNT*256;
        for(int e = bb*256+t; e<E; e+=stride)
            atomicAdd(&h[dst[e]>>6], 1);
        __syncthreads();
        for(int j=t;j<nbuck;j+=256) bcnt_part[bb*MAXBUCK + j] = h[j];
    } else if(b < 586){
        int idx4 = (b-457)*256 + t;
        if(idx4 < zfloat4) ((f32x4*)zbuf)[idx4] = (f32x4){0.f,0.f,0.f,0.f};
    } else {
        int i = (b-586)*256 + t;
        if(i>=N) return;
        int b2 = batch[i];
        if(i==0){ for(int g=0;g<=b2;g++) gstart[g]=0; }
        else { int bp=batch[i-1]; for(int g=bp+1; g<=b2; g++) gstart[g]=i; }
        if(i==N-1){ for(int g=b2+1; g<=NGRAPH; g++) gstart[g]=N; }
    }
}

// ---------- bucket scan ----------
__global__ void k_bscan(const int* bcnt_part, int nbuck, int* bbase, int* bcursor){
    __shared__ int s[1024];
    int t = threadIdx.x;
    int own = 0;
    if(t<nbuck){
        #pragma unroll 8
        for(int j=0;j<NCNT;j++) own += bcnt_part[j*MAXBUCK + t];
    }
    s[t] = own;
    __syncthreads();
    for(int off=1; off<1024; off<<=1){
        int a = (t>=off)? s[t-off] : 0;
        __syncthreads();
        s[t] += a;
        __syncthreads();
    }
    if(t<nbuck){ int ex = s[t]-own; bbase[t]=ex; bcursor[t]=ex; }
    if(t==nbuck-1) bbase[nbuck]=s[t];
}

// ---------- block-level reorder scatter (CHUNK=2048) ----------
__global__ __launch_bounds__(512) void k_bscatter(const int* src, const int* dst, int E,
                                                  int nbuck, int* bcursor, unsigned* ebuf){
    __shared__ int cnt[MAXBUCK];
    __shared__ int loff[MAXBUCK];
    __shared__ int cur[MAXBUCK];
    __shared__ int gbase[MAXBUCK];
    __shared__ int s[1024];
    __shared__ unsigned srt[CHUNK];
    int t = threadIdx.x;
    int c0 = blockIdx.x*CHUNK;
    int m = E - c0; if(m > CHUNK) m = CHUNK;
    for(int j=t;j<MAXBUCK;j+=512) cnt[j]=0;
    __syncthreads();
    unsigned rec[4];
    #pragma unroll
    for(int u=0;u<4;u++){
        int j = u*512 + t;
        if(j<m){
            int d = dst[c0+j];
            int sv = src[c0+j];
            rec[u] = ((unsigned)(d>>6)<<22) | ((unsigned)(d&63)<<16) | (unsigned)sv;
            atomicAdd(&cnt[d>>6], 1);
        } else rec[u] = 0xFFFFFFFFu;
    }
    __syncthreads();
    int v0 = (t<nbuck)? cnt[t]:0;
    int j2 = t+512;
    int v1 = (j2<nbuck)? cnt[j2]:0;
    s[t]=v0; s[j2]=v1;
    __syncthreads();
    for(int off=1; off<1024; off<<=1){
        int a = (t>=off)? s[t-off]:0;
        int b = s[j2-off];
        __syncthreads();
        s[t]+=a; s[j2]+=b;
        __syncthreads();
    }
    for(int j=t;j<nbuck;j+=512){
        int c = cnt[j];
        int ex = s[j]-c;
        loff[j]=ex; cur[j]=ex;
        if(c>0) gbase[j]=atomicAdd(&bcursor[j], c);
    }
    __syncthreads();
    #pragma unroll
    for(int u=0;u<4;u++){
        if(rec[u]!=0xFFFFFFFFu){
            int b = rec[u]>>22;
            int p = atomicAdd(&cur[b],1);
            srt[p]=rec[u];
        }
    }
    __syncthreads();
    for(int j=t;j<m;j+=512){
        unsigned r = srt[j];
        int b = r>>22;
        ebuf[gbase[b] + (j - loff[b])] = r;
    }
}

// ---------- layer-0 GAT + fused per-graph stats, 512 threads ----------
__global__ __launch_bounds__(512) void k_gat0(const unsigned* ebuf, const int* bbase,
                                              const float* x, const float* c_sd,
                                              const int* batch, const float* W0, const float* b0,
                                              int N, float* s0,
                                              unsigned short* csr16, int* rowstart,
                                              float* gsum, float* gsq,
                                              float* colsum, float* colsq){
    __shared__ unsigned raw[BCAP];
    __shared__ unsigned short esrc[BCAP];
    __shared__ int cnt[64], off[64], cur[64];
    __shared__ float s0l[64];
    __shared__ int bl[64];
    __shared__ float totl[512], totql[512];
    int t = threadIdx.x;
    int b = blockIdx.x;
    int e0 = bbase[b];
    int m = bbase[b+1]-e0; if(m>BCAP) m=BCAP;
    for(int j=t;j<m;j+=512) raw[j]=ebuf[e0+j];
    if(t<64) cnt[t]=0;
    __syncthreads();
    for(int j=t;j<m;j+=512) atomicAdd(&cnt[(raw[j]>>16)&63],1);
    __syncthreads();
    if(t<64){
        int v = cnt[t]; int inc = v;
        #pragma unroll
        for(int o=1;o<64;o<<=1){ int u = __shfl_up(inc,o); if(t>=o) inc+=u; }
        off[t]=inc-v; cur[t]=inc-v;
    }
    __syncthreads();
    for(int j=t;j<m;j+=512){
        unsigned r=raw[j]; int n=(r>>16)&63;
        int p=atomicAdd(&cur[n],1);
        esrc[p]=(unsigned short)(r&0xFFFF);
    }
    __syncthreads();
    for(int j=t;j<m;j+=512) csr16[e0+j]=esrc[j];
    if(t<64){
        rowstart[b*64+t] = e0 + off[t];
        int gid2 = b*64+t;
        bl[t] = (gid2<N) ? batch[gid2] : -1;
    }
    // per-node softmax-weighted scalar sum (8 lanes/node)
    {
        int n = t>>3, sub = t&7;
        int gid = b*64 + n;
        if(gid < N){
            float cs=c_sd[0], cd=c_sd[1];
            float xi = x[gid]; float adi = cd*xi;
            int r0=off[n], r1=cur[n];
            float den=0.f, num=0.f;
            if(sub==0){
                float ex = __expf(leaky(fmaf(cs,xi,adi)));
                den=ex; num=ex*xi;
            }
            for(int e=r0+sub;e<r1;e+=8){
                float xs = x[esrc[e]];
                float ee = __expf(leaky(fmaf(cs,xs,adi)));
                den += ee; num = fmaf(ee,xs,num);
            }
            den += __shfl_xor(den,1); den += __shfl_xor(den,2); den += __shfl_xor(den,4);
            num += __shfl_xor(num,1); num += __shfl_xor(num,2); num += __shfl_xor(num,4);
            if(sub==0){ float v = num*frcp(den+1e-16f); s0[gid]=v; s0l[n]=v; }
        }
    }
    __syncthreads();
    // fused stats: thread t -> col k=t&127, node range [(t>>7)*16, +16)
    {
        int k = t&127, quarter = t>>7;
        float wk = W0[k], bk = b0[k];
        int base = quarter*16;
        float sum=0.f, sq=0.f, tot=0.f, totq=0.f;
        int curg = -1;
        #pragma unroll 4
        for(int u=0;u<16;u++){
            int n = base+u;
            int g2 = bl[n];
            if(g2 < 0) break;
            float tv = ftanh(fmaf(s0l[n],wk,bk));
            if(g2!=curg){
                if(curg>=0){ atomicAdd(&gsum[curg*EMB+k],sum); atomicAdd(&gsq[curg*EMB+k],sq); }
                curg=g2; sum=0.f; sq=0.f;
            }
            sum+=tv; sq=fmaf(tv,tv,sq);
            tot+=tv; totq=fmaf(tv,tv,totq);
        }
        if(curg>=0){ atomicAdd(&gsum[curg*EMB+k],sum); atomicAdd(&gsq[curg*EMB+k],sq); }
        totl[t]=tot; totql[t]=totq;
    }
    __syncthreads();
    if(t<128){
        float a = totl[t]+totl[t+128]+totl[t+256]+totl[t+384];
        float q = totql[t]+totql[t+128]+totql[t+256]+totql[t+384];
        if(a!=0.f || q!=0.f){ atomicAdd(&colsum[t],a); atomicAdd(&colsq[t],q); }
    }
}

// ---------- fused P/Q + H materialization, one block per graph ----------
__global__ __launch_bounds__(256) void k_H(const float* s0, const int* gstart,
        const float* gsum, const float* gsq,
        const float* colsum, const float* colsq,
        const float* bn_g, const float* bn_b,
        const float* gn_w, const float* gn_b, const float* gn_ms,
        const float* W0, const float* b0, int N, f16_t* H){
    __shared__ float Pl[128], Ql[128];
    int g = blockIdx.x;
    int t = threadIdx.x;
    int i0 = gstart[g], i1 = gstart[g+1];
    if(t < 128){
        int k = t;
        float invN = frcp((float)N);
        float mu = colsum[k]*invN;
        float var = colsq[k]*invN - mu*mu;
        float A = bn_g[k]*rsqrtf(var+1e-5f);
        float Bs = bn_b[k]-mu*A;
        int c = i1-i0;
        float rc = frcp((float)(c>0?c:1));
        float m1 = gsum[g*EMB+k]*rc, m2 = gsq[g*EMB+k]*rc;
        float gmean = fmaf(A,m1,Bs);
        float B = Bs - gmean*gn_ms[k];
        float gvar = A*A*m2 + 2.f*A*B*m1 + B*B;
        float rg = rsqrtf(gvar+1e-5f);
        float w = gn_w[k];
        Pl[k] = w*A*rg;
        Ql[k] = fmaf(w*B, rg, gn_b[k]);
    }
    __syncthreads();
    int k0 = (t&15)*8;
    float w0r[8], b0r[8], Pr[8], Qr[8];
    #pragma unroll
    for(int u=0;u<8;u++){
        w0r[u]=W0[k0+u]; b0r[u]=b0[k0+u];
        Pr[u]=Pl[k0+u];  Qr[u]=Ql[k0+u];
    }
    int nn = i1 - i0;
    for(int base = 0; base < nn; base += 16){
        int ni = base + (t>>4);
        if(ni < nn){
            int i = i0 + ni;
            float s = s0[i];
            f16x8 o;
            #pragma unroll
            for(int u=0;u<8;u++)
                o[u] = (f16_t)fmaf(Pr[u], ftanh(fmaf(s,w0r[u],b0r[u])), Qr[u]);
            *(f16x8*)&H[(size_t)i*EMB + k0] = o;
        }
    }
}

// ---------- MFMA GEMM: h1 = H @ W1t^T, h1 stored as fp8 e4m3 ----------
__global__ __launch_bounds__(256) void k_gemm1(const f16_t* H, const f16_t* W1t,
        const float* as1, const float* ad1,
        int N, unsigned char* h1, float* a_s, float* a_d){
    __shared__ unsigned char ob[64*136];
    int t = threadIdx.x;
    int i0 = blockIdx.x*64;
    int w = t>>6, l = t&63;
    int lm = l&15, lq = l>>4;
    int arow = i0 + w*16 + lm; if(arow > N-1) arow = N-1;
    const f16_t* ap = &H[(size_t)arow*EMB + lq*8];
    f16x8 a[4];
    #pragma unroll
    for(int kt=0;kt<4;kt++) a[kt] = *(const f16x8*)&ap[kt*32];
    f32x4 acc[8];
    #pragma unroll
    for(int nt=0;nt<8;nt++) acc[nt] = (f32x4){0.f,0.f,0.f,0.f};
    #pragma unroll
    for(int nt=0;nt<8;nt++){
        const f16_t* bp = &W1t[(nt*16 + lm)*128 + lq*8];
        f16x8 b0v = *(const f16x8*)&bp[0];
        f16x8 b1v = *(const f16x8*)&bp[32];
        f16x8 b2v = *(const f16x8*)&bp[64];
        f16x8 b3v = *(const f16x8*)&bp[96];
        acc[nt] = __builtin_amdgcn_mfma_f32_16x16x32_f16(a[0], b0v, acc[nt], 0, 0, 0);
        acc[nt] = __builtin_amdgcn_mfma_f32_16x16x32_f16(a[1], b1v, acc[nt], 0, 0, 0);
        acc[nt] = __builtin_amdgcn_mfma_f32_16x16x32_f16(a[2], b2v, acc[nt], 0, 0, 0);
        acc[nt] = __builtin_amdgcn_mfma_f32_16x16x32_f16(a[3], b3v, acc[nt], 0, 0, 0);
    }
    float ps[4] = {0.f,0.f,0.f,0.f};
    float pd[4] = {0.f,0.f,0.f,0.f};
    #pragma unroll
    for(int nt=0;nt<8;nt++){
        int n = nt*16 + lm;
        float asv = as1[n], adv = ad1[n];
        #pragma unroll
        for(int r=0;r<4;r++){
            ps[r] = fmaf(acc[nt][r], asv, ps[r]);
            pd[r] = fmaf(acc[nt][r], adv, pd[r]);
        }
    }
    #pragma unroll
    for(int r=0;r<4;r++){
        #pragma unroll
        for(int off=1; off<16; off<<=1){
            ps[r] += __shfl_xor(ps[r], off);
            pd[r] += __shfl_xor(pd[r], off);
        }
    }
    if(lm==0){
        #pragma unroll
        for(int r=0;r<4;r++){
            int i = i0 + w*16 + lq*4 + r;
            if(i < N){ a_s[i]=ps[r]; a_d[i]=pd[r]; }
        }
    }
    #pragma unroll
    for(int nt=0;nt<8;nt++){
        int n = nt*16 + lm;
        #pragma unroll
        for(int r=0;r<4;r++){
            int row = w*16 + lq*4 + r;
            int pk = __builtin_amdgcn_cvt_pk_fp8_f32(acc[nt][r], acc[nt][r], 0, false);
            ob[row*136 + n] = (unsigned char)(pk & 0xFF);
        }
    }
    __syncthreads();
    #pragma unroll
    for(int c=0;c<4;c++){
        int idx = t + 256*c;
        int row = idx>>4, q = idx&15;
        int i = i0 + row;
        if(i < N){
            unsigned long long v = *(const unsigned long long*)&ob[row*136 + q*8];
            *(unsigned long long*)&h1[(size_t)i*EMB + q*8] = v;
        }
    }
}

// ---------- layer-1 GAT: wave per node, fp8 gather, packed shuffle ----------
__global__ __launch_bounds__(256) void k_gat1(const unsigned short* csr16, const int* rowstart,
                                              const unsigned char* h1, const float* a_s, const float* a_d,
                                              const float* b1, int N, f16_t* h2){
    int wave = threadIdx.x>>6, lane = threadIdx.x&63;
    int i = blockIdx.x*4 + wave;
    if(i>=N) return;
    int r0=rowstart[i], r1=rowstart[i+1]; int deg=r1-r0;
    float adi = a_d[i];
    float exs = __expf(leaky(a_s[i] + adi) - 4.f);
    const unsigned short* h1v = (const unsigned short*)h1;
    f32x2 hv = __builtin_amdgcn_cvt_pk_f32_fp8((int)h1v[(size_t)i*64 + lane], false);
    float accx0 = exs*hv.x, accy0 = exs*hv.y;
    float accx1=0.f, accy1=0.f, accx2=0.f, accy2=0.f, accx3=0.f, accy3=0.f;
    float denp = (lane==0)? exs : 0.f;
    for(int c=0;c<deg;c+=64){
        int e = c+lane;
        unsigned pk = 0;
        if(e<deg){
            int s = (int)csr16[r0+e];
            float ex = __expf(leaky(a_s[s]+adi)-4.f);
            denp += ex;
            pk = (unsigned)s | ((unsigned)__half_as_ushort(__float2half(ex))<<16);
        }
        int cnt = min(64, deg-c);
        int jj=0;
        for(; jj+7<cnt; jj+=8){
            unsigned p0=__shfl(pk,jj+0), p1=__shfl(pk,jj+1), p2=__shfl(pk,jj+2), p3=__shfl(pk,jj+3);
            unsigned p4=__shfl(pk,jj+4), p5=__shfl(pk,jj+5), p6=__shfl(pk,jj+6), p7=__shfl(pk,jj+7);
            unsigned short u0 = h1v[(size_t)(p0&0xFFFF)*64 + lane];
            unsigned short u1 = h1v[(size_t)(p1&0xFFFF)*64 + lane];
            unsigned short u2 = h1v[(size_t)(p2&0xFFFF)*64 + lane];
            unsigned short u3 = h1v[(size_t)(p3&0xFFFF)*64 + lane];
            unsigned short u4 = h1v[(size_t)(p4&0xFFFF)*64 + lane];
            unsigned short u5 = h1v[(size_t)(p5&0xFFFF)*64 + lane];
            unsigned short u6 = h1v[(size_t)(p6&0xFFFF)*64 + lane];
            unsigned short u7 = h1v[(size_t)(p7&0xFFFF)*64 + lane];
            f32x2 v0 = __builtin_amdgcn_cvt_pk_f32_fp8((int)u0, false);
            f32x2 v1 = __builtin_amdgcn_cvt_pk_f32_fp8((int)u1, false);
            f32x2 v2 = __builtin_amdgcn_cvt_pk_f32_fp8((int)u2, false);
            f32x2 v3 = __builtin_amdgcn_cvt_pk_f32_fp8((int)u3, false);
            f32x2 v4 = __builtin_amdgcn_cvt_pk_f32_fp8((int)u4, false);
            f32x2 v5 = __builtin_amdgcn_cvt_pk_f32_fp8((int)u5, false);
            f32x2 v6 = __builtin_amdgcn_cvt_pk_f32_fp8((int)u6, false);
            f32x2 v7 = __builtin_amdgcn_cvt_pk_f32_fp8((int)u7, false);
            float a0=__half2float(__ushort_as_half((unsigned short)(p0>>16)));
            float a1=__half2float(__ushort_as_half((unsigned short)(p1>>16)));
            float a2=__half2float(__ushort_as_half((unsigned short)(p2>>16)));
            float a3=__half2float(__ushort_as_half((unsigned short)(p3>>16)));
            float a4=__half2float(__ushort_as_half((unsigned short)(p4>>16)));
            float a5=__half2float(__ushort_as_half((unsigned short)(p5>>16)));
            float a6=__half2float(__ushort_as_half((unsigned short)(p6>>16)));
            float a7=__half2float(__ushort_as_half((unsigned short)(p7>>16)));
            accx0 = fmaf(a0, v0.x, accx0); accy0 = fmaf(a0, v0.y, accy0);
            accx1 = fmaf(a1, v1.x, accx1); accy1 = fmaf(a1, v1.y, accy1);
            accx2 = fmaf(a2, v2.x, accx2); accy2 = fmaf(a2, v2.y, accy2);
            accx3 = fmaf(a3, v3.x, accx3); accy3 = fmaf(a3, v3.y, accy3);
            accx0 = fmaf(a4, v4.x, accx0); accy0 = fmaf(a4, v4.y, accy0);
            accx1 = fmaf(a5, v5.x, accx1); accy1 = fmaf(a5, v5.y, accy1);
            accx2 = fmaf(a6, v6.x, accx2); accy2 = fmaf(a6, v6.y, accy2);
            accx3 = fmaf(a7, v7.x, accx3); accy3 = fmaf(a7, v7.y, accy3);
        }
        for(; jj<cnt; jj++){
            unsigned p0=__shfl(pk,jj);
            unsigned short u0 = h1v[(size_t)(p0&0xFFFF)*64 + lane];
            f32x2 v0 = __builtin_amdgcn_cvt_pk_f32_fp8((int)u0, false);
            float a0=__half2float(__ushort_as_half((unsigned short)(p0>>16)));
            accx0 = fmaf(a0, v0.x, accx0); accy0 = fmaf(a0, v0.y, accy0);
        }
    }
    accx0 += accx1 + accx2 + accx3;
    accy0 += accy1 + accy2 + accy3;
    for(int o=32; o; o>>=1) denp += __shfl_xor(denp, o);
    float rden = frcp(denp + 1e-16f);
    float2 bb = *(const float2*)&b1[lane*2];
    float ox = ftanh(fmaf(accx0, rden, bb.x));
    float oy = ftanh(fmaf(accy0, rden, bb.y));
    *(__half2*)&h2[(size_t)i*EMB + lane*2] = __floats2half2_rn(ox, oy);
}

// ---------- per-graph max+mean pool (fp16 in) -> fp16 ----------
__global__ void k_pool(const f16_t* h2, const int* gstart, f16_t* pooled){
    int g=blockIdx.x, k=threadIdx.x;
    const __half2* h2v = (const __half2*)h2;
    int i0=gstart[g], i1=gstart[g+1];
    float2 mx = {-1e30f,-1e30f}, sm = {0.f,0.f};
    for(int i=i0;i<i1;i++){
        float2 v=__half22float2(h2v[(size_t)i*64+k]);
        mx.x=fmaxf(mx.x,v.x); mx.y=fmaxf(mx.y,v.y);
        sm.x+=v.x; sm.y+=v.y;
    }
    float c = frcp((float)((i1-i0)>0 ? (i1-i0) : 1));
    pooled[g*256+2*k  ]=(f16_t)mx.x;
    pooled[g*256+2*k+1]=(f16_t)mx.y;
    pooled[g*256+128+2*k  ]=(f16_t)(sm.x*c);
    pooled[g*256+128+2*k+1]=(f16_t)(sm.y*c);
}

// ---------- MFMA out GEMM ----------
__global__ __launch_bounds__(256) void k_out(const f16_t* pooled, const f16_t* WoutT,
                                             const float* bout, int OUT, float* out){
    int t = threadIdx.x;
    int w = t>>6, l = t&63;
    int lm = l&15, lq = l>>4;
    int m0 = (blockIdx.y*4 + w)*16;
    int n0 = blockIdx.x*64;
    f16x8 a[8];
    const f16_t* ap = &pooled[(m0+lm)*256 + lq*8];
    #pragma unroll
    for(int kt=0;kt<8;kt++) a[kt] = *(const f16x8*)&ap[kt*32];
    f32x4 acc[4];
    #pragma unroll
    for(int nt=0;nt<4;nt++) acc[nt] = (f32x4){0.f,0.f,0.f,0.f};
    #pragma unroll
    for(int nt=0;nt<4;nt++){
        const f16_t* bp = &WoutT[(size_t)(n0 + nt*16 + lm)*256 + lq*8];
        #pragma unroll
        for(int kt=0;kt<8;kt++){
            f16x8 b = *(const f16x8*)&bp[kt*32];
            acc[nt] = __builtin_amdgcn_mfma_f32_16x16x32_f16(a[kt], b, acc[nt], 0, 0, 0);
        }
    }
    #pragma unroll
    for(int nt=0;nt<4;nt++){
        int n = n0 + nt*16 + lm;
        if(n >= OUT) continue;
        float bv = bout[n];
        #pragma unroll
        for(int r=0;r<4;r++){
            int m = m0 + lq*4 + r;
            out[(size_t)m*OUT + n] = acc[nt][r] + bv;
        }
    }
}

extern "C" void kernel_launch(void* const* d_in, const int* in_sizes, int n_in,
                              void* d_out, int out_size, void* d_ws, size_t ws_size,
                              hipStream_t stream) {
    const float* x    = (const float*)d_in[0];
    const int*   eidx = (const int*)d_in[1];
    const int*   batch= (const int*)d_in[2];
    const float* W0   = (const float*)d_in[4];
    const float* as0  = (const float*)d_in[5];
    const float* ad0  = (const float*)d_in[6];
    const float* b0   = (const float*)d_in[7];
    const float* W1   = (const float*)d_in[8];
    const float* as1  = (const float*)d_in[9];
    const float* ad1  = (const float*)d_in[10];
    const float* b1   = (const float*)d_in[11];
    const float* bn_g = (const float*)d_in[12];
    const float* bn_b = (const float*)d_in[13];
    const float* gn_w = (const float*)d_in[14];
    const float* gn_b = (const float*)d_in[15];
    const float* gn_ms= (const float*)d_in[16];
    const float* Wout = (const float*)d_in[17];
    const float* bout = (const float*)d_in[18];

    int N = in_sizes[0];
    int E = in_sizes[1]/2;
    int OUT = out_size / NGRAPH;
    const int* srcp = eidx;
    const int* dstp = eidx + E;
    int nbuck = (N+63)>>6;

    char* w = (char*)d_ws;
    auto alloc = [&](size_t bytes) -> void* {
        void* p = (void*)w; w += (bytes+255)&~(size_t)255; return p;
    };
    int zfloats   = 256 + 2*NGRAPH*EMB;
    float* zbuf   = (float*)alloc((size_t)zfloats*4);
    float* colsum = zbuf;
    float* colsq  = zbuf + 128;
    float* gsum   = zbuf + 256;
    float* gsq    = gsum + (size_t)NGRAPH*EMB;
    int* bcnt_part= (int*)alloc((size_t)NCNT*MAXBUCK*4);
    int* bbase    = (int*)alloc((MAXBUCK+1)*4);
    int* bcursor  = (int*)alloc(MAXBUCK*4);
    unsigned* ebuf= (unsigned*)alloc((size_t)E*4);
    unsigned short* csr16 = (unsigned short*)alloc((size_t)E*2);
    int* rowstart = (int*)alloc((size_t)(MAXBUCK*64+64)*4);
    float* c_sd   = (float*)alloc(256);
    float* s0     = (float*)alloc((size_t)N*4);
    int* gstart   = (int*)alloc((NGRAPH+1)*4);
    f16_t* Hbuf   = (f16_t*)alloc((size_t)N*EMB*2);
    unsigned char* h1 = (unsigned char*)alloc((size_t)N*EMB);
    f16_t* h2     = (f16_t*)alloc((size_t)N*EMB*2);
    float* a_sv   = (float*)alloc((size_t)N*4);
    float* a_dv   = (float*)alloc((size_t)N*4);
    f16_t* pooled = (f16_t*)alloc(NGRAPH*256*2);
    f16_t* w1t    = (f16_t*)alloc(128*128*2);
    f16_t* woutt  = (f16_t*)alloc((size_t)4352*256*2);

    int zfloat4 = zfloats/4;
    int miscgrid = 586 + (N+255)/256;
    k_misc<<<miscgrid,256,0,stream>>>(W0,as0,ad0,c_sd,W1,w1t,Wout,OUT,woutt,
                                      dstp,E,nbuck,bcnt_part,zbuf,zfloat4,batch,N,gstart);
    k_bscan<<<1,1024,0,stream>>>(bcnt_part,nbuck,bbase,bcursor);
    int nchunk = (E+CHUNK-1)/CHUNK;
    k_bscatter<<<nchunk,512,0,stream>>>(srcp,dstp,E,nbuck,bcursor,ebuf);
    k_gat0<<<nbuck,512,0,stream>>>(ebuf,bbase,x,c_sd,batch,W0,b0,N,s0,csr16,rowstart,
                                   gsum,gsq,colsum,colsq);
    k_H<<<NGRAPH,256,0,stream>>>(s0,gstart,gsum,gsq,colsum,colsq,
                                 bn_g,bn_b,gn_w,gn_b,gn_ms,W0,b0,N,Hbuf);
    k_gemm1<<<(N+63)/64,256,0,stream>>>(Hbuf,w1t,as1,ad1,N,h1,a_sv,a_dv);
    k_gat1<<<(N+3)/4,256,0,stream>>>(csr16,rowstart,h1,a_sv,a_dv,b1,N,h2);
    k_pool<<<NGRAPH,64,0,stream>>>(h2,gstart,pooled);
    dim3 og(68, 8);
    k_out<<<og,256,0,stream>>>(pooled,woutt,bout,OUT,(float*)d_out);
}

// Round 16
// 176.730 us; speedup vs baseline: 1.0118x; 1.0118x over previous
//
#include <hip/hip_runtime.h>
#include <hip/hip_fp16.h>
#include <math.h>

#define EMB 128
#define NGRAPH 512
#define MAXBUCK 800          // max buckets (N up to 51200 @ 64 nodes/bucket)
#define BCAP 1536            // per-bucket edge capacity
#define CHUNK 4096           // edges per bscatter block (R13/R14 optimum; 2048 regressed)
#define NCNT 120             // bcount blocks

typedef _Float16 f16_t;
typedef _Float16 f16x8 __attribute__((ext_vector_type(8)));
typedef float f32x4 __attribute__((ext_vector_type(4)));
typedef float f32x2 __attribute__((ext_vector_type(2)));

__device__ __forceinline__ float leaky(float v){ return v > 0.f ? v : 0.2f*v; }
__device__ __forceinline__ float ftanh(float x){
    float u = __expf(2.f*x);
    return 1.f - 2.f*__builtin_amdgcn_rcpf(u + 1.f);
}
__device__ __forceinline__ float frcp(float x){ return __builtin_amdgcn_rcpf(x); }

// ---------- fused independent prep ----------
__global__ __launch_bounds__(256) void k_misc(const float* W0, const float* as0, const float* ad0,
                                              float* c_sd, const float* W1, f16_t* W1t,
                                              const float* Wout, int OUT, f16_t* WoutT,
                                              const int* dst, int E, int nbuck, int* bcnt_part,
                                              float* zbuf, int zfloat4,
                                              const int* batch, int N, int* gstart){
    __shared__ f16_t lt[64*68];
    __shared__ float s1[128], s2[128];
    __shared__ int h[MAXBUCK];
    int b = blockIdx.x;
    int t = threadIdx.x;
    if(b < 272){
        int n0 = (b%68)*64, k0 = (b/68)*64;
        #pragma unroll
        for(int j=0;j<16;j++){
            int k_l = (t>>6)*16 + j;
            int n_l = t&63;
            int n = n0+n_l;
            float v = (n < OUT) ? Wout[(size_t)(k0+k_l)*OUT + n] : 0.f;
            lt[n_l*68 + k_l] = (f16_t)v;
        }
        __syncthreads();
        #pragma unroll
        for(int j=0;j<16;j++){
            int n_l = (t>>6)*16 + j;
            int k_l = t&63;
            WoutT[(size_t)(n0+n_l)*256 + k0 + k_l] = lt[n_l*68 + k_l];
        }
    } else if(b < 336){
        int idx = (b-272)*256 + t;
        int n = idx>>7, k = idx&127;
        W1t[n*128+k] = (f16_t)W1[k*128+n];
    } else if(b == 336){
        if(t<128){ float w = W0[t]; s1[t]=w*as0[t]; s2[t]=w*ad0[t]; }
        __syncthreads();
        for(int off=64; off>0; off>>=1){
            if(t<off){ s1[t]+=s1[t+off]; s2[t]+=s2[t+off]; }
            __syncthreads();
        }
        if(t==0){ c_sd[0]=s1[0]; c_sd[1]=s2[0]; }
    } else if(b < 457){
        int bb = b-337;
        for(int j=t;j<MAXBUCK;j+=256) h[j]=0;
        __syncthreads();
        int stride = NCNT*256;
        for(int e = bb*256+t; e<E; e+=stride)
            atomicAdd(&h[dst[e]>>6], 1);
        __syncthreads();
        for(int j=t;j<nbuck;j+=256) bcnt_part[bb*MAXBUCK + j] = h[j];
    } else if(b < 586){
        int idx4 = (b-457)*256 + t;
        if(idx4 < zfloat4) ((f32x4*)zbuf)[idx4] = (f32x4){0.f,0.f,0.f,0.f};
    } else {
        int i = (b-586)*256 + t;
        if(i>=N) return;
        int b2 = batch[i];
        if(i==0){ for(int g=0;g<=b2;g++) gstart[g]=0; }
        else { int bp=batch[i-1]; for(int g=bp+1; g<=b2; g++) gstart[g]=i; }
        if(i==N-1){ for(int g=b2+1; g<=NGRAPH; g++) gstart[g]=N; }
    }
}

// ---------- bucket scan ----------
__global__ void k_bscan(const int* bcnt_part, int nbuck, int* bbase, int* bcursor){
    __shared__ int s[1024];
    int t = threadIdx.x;
    int own = 0;
    if(t<nbuck){
        #pragma unroll 8
        for(int j=0;j<NCNT;j++) own += bcnt_part[j*MAXBUCK + t];
    }
    s[t] = own;
    __syncthreads();
    for(int off=1; off<1024; off<<=1){
        int a = (t>=off)? s[t-off] : 0;
        __syncthreads();
        s[t] += a;
        __syncthreads();
    }
    if(t<nbuck){ int ex = s[t]-own; bbase[t]=ex; bcursor[t]=ex; }
    if(t==nbuck-1) bbase[nbuck]=s[t];
}

// ---------- block-level reorder scatter ----------
__global__ __launch_bounds__(512) void k_bscatter(const int* src, const int* dst, int E,
                                                  int nbuck, int* bcursor, unsigned* ebuf){
    __shared__ int cnt[MAXBUCK];
    __shared__ int loff[MAXBUCK];
    __shared__ int cur[MAXBUCK];
    __shared__ int gbase[MAXBUCK];
    __shared__ int s[1024];
    __shared__ unsigned srt[CHUNK];
    int t = threadIdx.x;
    int c0 = blockIdx.x*CHUNK;
    int m = E - c0; if(m > CHUNK) m = CHUNK;
    for(int j=t;j<MAXBUCK;j+=512) cnt[j]=0;
    __syncthreads();
    unsigned rec[8];
    #pragma unroll
    for(int u=0;u<8;u++){
        int j = u*512 + t;
        if(j<m){
            int d = dst[c0+j];
            int sv = src[c0+j];
            rec[u] = ((unsigned)(d>>6)<<22) | ((unsigned)(d&63)<<16) | (unsigned)sv;
            atomicAdd(&cnt[d>>6], 1);
        } else rec[u] = 0xFFFFFFFFu;
    }
    __syncthreads();
    int v0 = (t<nbuck)? cnt[t]:0;
    int j2 = t+512;
    int v1 = (j2<nbuck)? cnt[j2]:0;
    s[t]=v0; s[j2]=v1;
    __syncthreads();
    for(int off=1; off<1024; off<<=1){
        int a = (t>=off)? s[t-off]:0;
        int b = s[j2-off];
        __syncthreads();
        s[t]+=a; s[j2]+=b;
        __syncthreads();
    }
    for(int j=t;j<nbuck;j+=512){
        int c = cnt[j];
        int ex = s[j]-c;
        loff[j]=ex; cur[j]=ex;
        if(c>0) gbase[j]=atomicAdd(&bcursor[j], c);
    }
    __syncthreads();
    #pragma unroll
    for(int u=0;u<8;u++){
        if(rec[u]!=0xFFFFFFFFu){
            int b = rec[u]>>22;
            int p = atomicAdd(&cur[b],1);
            srt[p]=rec[u];
        }
    }
    __syncthreads();
    for(int j=t;j<m;j+=512){
        unsigned r = srt[j];
        int b = r>>22;
        ebuf[gbase[b] + (j - loff[b])] = r;
    }
}

// ---------- layer-0 GAT + fused per-graph stats ----------
__global__ __launch_bounds__(256) void k_gat0(const unsigned* ebuf, const int* bbase,
                                              const float* x, const float* c_sd,
                                              const int* batch, const float* W0, const float* b0,
                                              int N, float* s0,
                                              unsigned short* csr16, int* rowstart,
                                              float* gsum, float* gsq,
                                              float* colsum, float* colsq){
    __shared__ unsigned raw[BCAP];
    __shared__ unsigned short esrc[BCAP];
    __shared__ int cnt[64], off[64], cur[64];
    __shared__ float s0l[64];
    __shared__ int bl[64];
    __shared__ float totl[256], totql[256];
    int t = threadIdx.x;
    int b = blockIdx.x;
    int e0 = bbase[b];
    int m = bbase[b+1]-e0; if(m>BCAP) m=BCAP;
    for(int j=t;j<m;j+=256) raw[j]=ebuf[e0+j];
    if(t<64) cnt[t]=0;
    __syncthreads();
    for(int j=t;j<m;j+=256) atomicAdd(&cnt[(raw[j]>>16)&63],1);
    __syncthreads();
    if(t<64){
        int v = cnt[t]; int inc = v;
        #pragma unroll
        for(int o=1;o<64;o<<=1){ int u = __shfl_up(inc,o); if(t>=o) inc+=u; }
        off[t]=inc-v; cur[t]=inc-v;
    }
    __syncthreads();
    for(int j=t;j<m;j+=256){
        unsigned r=raw[j]; int n=(r>>16)&63;
        int p=atomicAdd(&cur[n],1);
        esrc[p]=(unsigned short)(r&0xFFFF);
    }
    __syncthreads();
    for(int j=t;j<m;j+=256) csr16[e0+j]=esrc[j];
    if(t<64){
        rowstart[b*64+t] = e0 + off[t];
        int gid2 = b*64+t;
        bl[t] = (gid2<N) ? batch[gid2] : -1;
    }
    {
        int n = t>>2, sub = t&3;
        int gid = b*64 + n;
        if(gid < N){
            float cs=c_sd[0], cd=c_sd[1];
            float xi = x[gid]; float adi = cd*xi;
            int r0=off[n], r1=cur[n];
            float den=0.f, num=0.f;
            if(sub==0){
                float ex = __expf(leaky(fmaf(cs,xi,adi)));
                den=ex; num=ex*xi;
            }
            for(int e=r0+sub;e<r1;e+=4){
                float xs = x[esrc[e]];
                float ee = __expf(leaky(fmaf(cs,xs,adi)));
                den += ee; num = fmaf(ee,xs,num);
            }
            den += __shfl_xor(den,1); den += __shfl_xor(den,2);
            num += __shfl_xor(num,1); num += __shfl_xor(num,2);
            if(sub==0){ float v = num*frcp(den+1e-16f); s0[gid]=v; s0l[n]=v; }
        }
    }
    __syncthreads();
    {
        int k = t&127, half = t>>7;
        float wk = W0[k], bk = b0[k];
        int base = half*32;
        float sum=0.f, sq=0.f, tot=0.f, totq=0.f;
        int curg = -1;
        #pragma unroll 4
        for(int u=0;u<32;u++){
            int n = base+u;
            int g2 = bl[n];
            if(g2 < 0) break;
            float tv = ftanh(fmaf(s0l[n],wk,bk));
            if(g2!=curg){
                if(curg>=0){ atomicAdd(&gsum[curg*EMB+k],sum); atomicAdd(&gsq[curg*EMB+k],sq); }
                curg=g2; sum=0.f; sq=0.f;
            }
            sum+=tv; sq=fmaf(tv,tv,sq);
            tot+=tv; totq=fmaf(tv,tv,totq);
        }
        if(curg>=0){ atomicAdd(&gsum[curg*EMB+k],sum); atomicAdd(&gsq[curg*EMB+k],sq); }
        totl[t]=tot; totql[t]=totq;
    }
    __syncthreads();
    if(t<128){
        float a = totl[t]+totl[t+128];
        float q = totql[t]+totql[t+128];
        if(a!=0.f || q!=0.f){ atomicAdd(&colsum[t],a); atomicAdd(&colsq[t],q); }
    }
}

// ---------- fused P/Q + H materialization, one block per graph ----------
__global__ __launch_bounds__(256) void k_H(const float* s0, const int* gstart,
        const float* gsum, const float* gsq,
        const float* colsum, const float* colsq,
        const float* bn_g, const float* bn_b,
        const float* gn_w, const float* gn_b, const float* gn_ms,
        const float* W0, const float* b0, int N, f16_t* H){
    __shared__ float Pl[128], Ql[128];
    int g = blockIdx.x;
    int t = threadIdx.x;
    int i0 = gstart[g], i1 = gstart[g+1];
    if(t < 128){
        int k = t;
        float invN = frcp((float)N);
        float mu = colsum[k]*invN;
        float var = colsq[k]*invN - mu*mu;
        float A = bn_g[k]*rsqrtf(var+1e-5f);
        float Bs = bn_b[k]-mu*A;
        int c = i1-i0;
        float rc = frcp((float)(c>0?c:1));
        float m1 = gsum[g*EMB+k]*rc, m2 = gsq[g*EMB+k]*rc;
        float gmean = fmaf(A,m1,Bs);
        float B = Bs - gmean*gn_ms[k];
        float gvar = A*A*m2 + 2.f*A*B*m1 + B*B;
        float rg = rsqrtf(gvar+1e-5f);
        float w = gn_w[k];
        Pl[k] = w*A*rg;
        Ql[k] = fmaf(w*B, rg, gn_b[k]);
    }
    __syncthreads();
    int k0 = (t&15)*8;
    float w0r[8], b0r[8], Pr[8], Qr[8];
    #pragma unroll
    for(int u=0;u<8;u++){
        w0r[u]=W0[k0+u]; b0r[u]=b0[k0+u];
        Pr[u]=Pl[k0+u];  Qr[u]=Ql[k0+u];
    }
    int nn = i1 - i0;
    for(int base = 0; base < nn; base += 16){
        int ni = base + (t>>4);
        if(ni < nn){
            int i = i0 + ni;
            float s = s0[i];
            f16x8 o;
            #pragma unroll
            for(int u=0;u<8;u++)
                o[u] = (f16_t)fmaf(Pr[u], ftanh(fmaf(s,w0r[u],b0r[u])), Qr[u]);
            *(f16x8*)&H[(size_t)i*EMB + k0] = o;
        }
    }
}

// ---------- MFMA GEMM: h1 = H @ W1t^T, h1 stored as fp8 e4m3 ----------
__global__ __launch_bounds__(256) void k_gemm1(const f16_t* H, const f16_t* W1t,
        const float* as1, const float* ad1,
        int N, unsigned char* h1, float* a_s, float* a_d){
    __shared__ unsigned char ob[64*136];
    int t = threadIdx.x;
    int i0 = blockIdx.x*64;
    int w = t>>6, l = t&63;
    int lm = l&15, lq = l>>4;
    int arow = i0 + w*16 + lm; if(arow > N-1) arow = N-1;
    const f16_t* ap = &H[(size_t)arow*EMB + lq*8];
    f16x8 a[4];
    #pragma unroll
    for(int kt=0;kt<4;kt++) a[kt] = *(const f16x8*)&ap[kt*32];
    f32x4 acc[8];
    #pragma unroll
    for(int nt=0;nt<8;nt++) acc[nt] = (f32x4){0.f,0.f,0.f,0.f};
    #pragma unroll
    for(int nt=0;nt<8;nt++){
        const f16_t* bp = &W1t[(nt*16 + lm)*128 + lq*8];
        f16x8 b0v = *(const f16x8*)&bp[0];
        f16x8 b1v = *(const f16x8*)&bp[32];
        f16x8 b2v = *(const f16x8*)&bp[64];
        f16x8 b3v = *(const f16x8*)&bp[96];
        acc[nt] = __builtin_amdgcn_mfma_f32_16x16x32_f16(a[0], b0v, acc[nt], 0, 0, 0);
        acc[nt] = __builtin_amdgcn_mfma_f32_16x16x32_f16(a[1], b1v, acc[nt], 0, 0, 0);
        acc[nt] = __builtin_amdgcn_mfma_f32_16x16x32_f16(a[2], b2v, acc[nt], 0, 0, 0);
        acc[nt] = __builtin_amdgcn_mfma_f32_16x16x32_f16(a[3], b3v, acc[nt], 0, 0, 0);
    }
    float ps[4] = {0.f,0.f,0.f,0.f};
    float pd[4] = {0.f,0.f,0.f,0.f};
    #pragma unroll
    for(int nt=0;nt<8;nt++){
        int n = nt*16 + lm;
        float asv = as1[n], adv = ad1[n];
        #pragma unroll
        for(int r=0;r<4;r++){
            ps[r] = fmaf(acc[nt][r], asv, ps[r]);
            pd[r] = fmaf(acc[nt][r], adv, pd[r]);
        }
    }
    #pragma unroll
    for(int r=0;r<4;r++){
        #pragma unroll
        for(int off=1; off<16; off<<=1){
            ps[r] += __shfl_xor(ps[r], off);
            pd[r] += __shfl_xor(pd[r], off);
        }
    }
    if(lm==0){
        #pragma unroll
        for(int r=0;r<4;r++){
            int i = i0 + w*16 + lq*4 + r;
            if(i < N){ a_s[i]=ps[r]; a_d[i]=pd[r]; }
        }
    }
    #pragma unroll
    for(int nt=0;nt<8;nt++){
        int n = nt*16 + lm;
        #pragma unroll
        for(int r=0;r<4;r++){
            int row = w*16 + lq*4 + r;
            int pk = __builtin_amdgcn_cvt_pk_fp8_f32(acc[nt][r], acc[nt][r], 0, false);
            ob[row*136 + n] = (unsigned char)(pk & 0xFF);
        }
    }
    __syncthreads();
    #pragma unroll
    for(int c=0;c<4;c++){
        int idx = t + 256*c;
        int row = idx>>4, q = idx&15;
        int i = i0 + row;
        if(i < N){
            unsigned long long v = *(const unsigned long long*)&ob[row*136 + q*8];
            *(unsigned long long*)&h1[(size_t)i*EMB + q*8] = v;
        }
    }
}

// ---------- layer-1 GAT: wave per node, fp8 gather, packed shuffle ----------
__global__ __launch_bounds__(256) void k_gat1(const unsigned short* csr16, const int* rowstart,
                                              const unsigned char* h1, const float* a_s, const float* a_d,
                                              const float* b1, int N, f16_t* h2){
    int wave = threadIdx.x>>6, lane = threadIdx.x&63;
    int i = blockIdx.x*4 + wave;
    if(i>=N) return;
    int r0=rowstart[i], r1=rowstart[i+1]; int deg=r1-r0;
    float adi = a_d[i];
    float exs = __expf(leaky(a_s[i] + adi) - 4.f);
    const unsigned short* h1v = (const unsigned short*)h1;
    f32x2 hv = __builtin_amdgcn_cvt_pk_f32_fp8((int)h1v[(size_t)i*64 + lane], false);
    float accx0 = exs*hv.x, accy0 = exs*hv.y;
    float accx1=0.f, accy1=0.f, accx2=0.f, accy2=0.f, accx3=0.f, accy3=0.f;
    float denp = (lane==0)? exs : 0.f;
    for(int c=0;c<deg;c+=64){
        int e = c+lane;
        unsigned pk = 0;
        if(e<deg){
            int s = (int)csr16[r0+e];
            float ex = __expf(leaky(a_s[s]+adi)-4.f);
            denp += ex;
            pk = (unsigned)s | ((unsigned)__half_as_ushort(__float2half(ex))<<16);
        }
        int cnt = min(64, deg-c);
        int jj=0;
        for(; jj+7<cnt; jj+=8){
            unsigned p0=__shfl(pk,jj+0), p1=__shfl(pk,jj+1), p2=__shfl(pk,jj+2), p3=__shfl(pk,jj+3);
            unsigned p4=__shfl(pk,jj+4), p5=__shfl(pk,jj+5), p6=__shfl(pk,jj+6), p7=__shfl(pk,jj+7);
            unsigned short u0 = h1v[(size_t)(p0&0xFFFF)*64 + lane];
            unsigned short u1 = h1v[(size_t)(p1&0xFFFF)*64 + lane];
            unsigned short u2 = h1v[(size_t)(p2&0xFFFF)*64 + lane];
            unsigned short u3 = h1v[(size_t)(p3&0xFFFF)*64 + lane];
            unsigned short u4 = h1v[(size_t)(p4&0xFFFF)*64 + lane];
            unsigned short u5 = h1v[(size_t)(p5&0xFFFF)*64 + lane];
            unsigned short u6 = h1v[(size_t)(p6&0xFFFF)*64 + lane];
            unsigned short u7 = h1v[(size_t)(p7&0xFFFF)*64 + lane];
            f32x2 v0 = __builtin_amdgcn_cvt_pk_f32_fp8((int)u0, false);
            f32x2 v1 = __builtin_amdgcn_cvt_pk_f32_fp8((int)u1, false);
            f32x2 v2 = __builtin_amdgcn_cvt_pk_f32_fp8((int)u2, false);
            f32x2 v3 = __builtin_amdgcn_cvt_pk_f32_fp8((int)u3, false);
            f32x2 v4 = __builtin_amdgcn_cvt_pk_f32_fp8((int)u4, false);
            f32x2 v5 = __builtin_amdgcn_cvt_pk_f32_fp8((int)u5, false);
            f32x2 v6 = __builtin_amdgcn_cvt_pk_f32_fp8((int)u6, false);
            f32x2 v7 = __builtin_amdgcn_cvt_pk_f32_fp8((int)u7, false);
            float a0=__half2float(__ushort_as_half((unsigned short)(p0>>16)));
            float a1=__half2float(__ushort_as_half((unsigned short)(p1>>16)));
            float a2=__half2float(__ushort_as_half((unsigned short)(p2>>16)));
            float a3=__half2float(__ushort_as_half((unsigned short)(p3>>16)));
            float a4=__half2float(__ushort_as_half((unsigned short)(p4>>16)));
            float a5=__half2float(__ushort_as_half((unsigned short)(p5>>16)));
            float a6=__half2float(__ushort_as_half((unsigned short)(p6>>16)));
            float a7=__half2float(__ushort_as_half((unsigned short)(p7>>16)));
            accx0 = fmaf(a0, v0.x, accx0); accy0 = fmaf(a0, v0.y, accy0);
            accx1 = fmaf(a1, v1.x, accx1); accy1 = fmaf(a1, v1.y, accy1);
            accx2 = fmaf(a2, v2.x, accx2); accy2 = fmaf(a2, v2.y, accy2);
            accx3 = fmaf(a3, v3.x, accx3); accy3 = fmaf(a3, v3.y, accy3);
            accx0 = fmaf(a4, v4.x, accx0); accy0 = fmaf(a4, v4.y, accy0);
            accx1 = fmaf(a5, v5.x, accx1); accy1 = fmaf(a5, v5.y, accy1);
            accx2 = fmaf(a6, v6.x, accx2); accy2 = fmaf(a6, v6.y, accy2);
            accx3 = fmaf(a7, v7.x, accx3); accy3 = fmaf(a7, v7.y, accy3);
        }
        for(; jj<cnt; jj++){
            unsigned p0=__shfl(pk,jj);
            unsigned short u0 = h1v[(size_t)(p0&0xFFFF)*64 + lane];
            f32x2 v0 = __builtin_amdgcn_cvt_pk_f32_fp8((int)u0, false);
            float a0=__half2float(__ushort_as_half((unsigned short)(p0>>16)));
            accx0 = fmaf(a0, v0.x, accx0); accy0 = fmaf(a0, v0.y, accy0);
        }
    }
    accx0 += accx1 + accx2 + accx3;
    accy0 += accy1 + accy2 + accy3;
    for(int o=32; o; o>>=1) denp += __shfl_xor(denp, o);
    float rden = frcp(denp + 1e-16f);
    float2 bb = *(const float2*)&b1[lane*2];
    float ox = ftanh(fmaf(accx0, rden, bb.x));
    float oy = ftanh(fmaf(accy0, rden, bb.y));
    *(__half2*)&h2[(size_t)i*EMB + lane*2] = __floats2half2_rn(ox, oy);
}

// ---------- per-graph max+mean pool (fp16 in) -> fp16 ----------
__global__ void k_pool(const f16_t* h2, const int* gstart, f16_t* pooled){
    int g=blockIdx.x, k=threadIdx.x;
    const __half2* h2v = (const __half2*)h2;
    int i0=gstart[g], i1=gstart[g+1];
    float2 mx = {-1e30f,-1e30f}, sm = {0.f,0.f};
    for(int i=i0;i<i1;i++){
        float2 v=__half22float2(h2v[(size_t)i*64+k]);
        mx.x=fmaxf(mx.x,v.x); mx.y=fmaxf(mx.y,v.y);
        sm.x+=v.x; sm.y+=v.y;
    }
    float c = frcp((float)((i1-i0)>0 ? (i1-i0) : 1));
    pooled[g*256+2*k  ]=(f16_t)mx.x;
    pooled[g*256+2*k+1]=(f16_t)mx.y;
    pooled[g*256+128+2*k  ]=(f16_t)(sm.x*c);
    pooled[g*256+128+2*k+1]=(f16_t)(sm.y*c);
}

// ---------- MFMA out GEMM ----------
__global__ __launch_bounds__(256) void k_out(const f16_t* pooled, const f16_t* WoutT,
                                             const float* bout, int OUT, float* out){
    int t = threadIdx.x;
    int w = t>>6, l = t&63;
    int lm = l&15, lq = l>>4;
    int m0 = (blockIdx.y*4 + w)*16;
    int n0 = blockIdx.x*64;
    f16x8 a[8];
    const f16_t* ap = &pooled[(m0+lm)*256 + lq*8];
    #pragma unroll
    for(int kt=0;kt<8;kt++) a[kt] = *(const f16x8*)&ap[kt*32];
    f32x4 acc[4];
    #pragma unroll
    for(int nt=0;nt<4;nt++) acc[nt] = (f32x4){0.f,0.f,0.f,0.f};
    #pragma unroll
    for(int nt=0;nt<4;nt++){
        const f16_t* bp = &WoutT[(size_t)(n0 + nt*16 + lm)*256 + lq*8];
        #pragma unroll
        for(int kt=0;kt<8;kt++){
            f16x8 b = *(const f16x8*)&bp[kt*32];
            acc[nt] = __builtin_amdgcn_mfma_f32_16x16x32_f16(a[kt], b, acc[nt], 0, 0, 0);
        }
    }
    #pragma unroll
    for(int nt=0;nt<4;nt++){
        int n = n0 + nt*16 + lm;
        if(n >= OUT) continue;
        float bv = bout[n];
        #pragma unroll
        for(int r=0;r<4;r++){
            int m = m0 + lq*4 + r;
            out[(size_t)m*OUT + n] = acc[nt][r] + bv;
        }
    }
}

extern "C" void kernel_launch(void* const* d_in, const int* in_sizes, int n_in,
                              void* d_out, int out_size, void* d_ws, size_t ws_size,
                              hipStream_t stream) {
    const float* x    = (const float*)d_in[0];
    const int*   eidx = (const int*)d_in[1];
    const int*   batch= (const int*)d_in[2];
    const float* W0   = (const float*)d_in[4];
    const float* as0  = (const float*)d_in[5];
    const float* ad0  = (const float*)d_in[6];
    const float* b0   = (const float*)d_in[7];
    const float* W1   = (const float*)d_in[8];
    const float* as1  = (const float*)d_in[9];
    const float* ad1  = (const float*)d_in[10];
    const float* b1   = (const float*)d_in[11];
    const float* bn_g = (const float*)d_in[12];
    const float* bn_b = (const float*)d_in[13];
    const float* gn_w = (const float*)d_in[14];
    const float* gn_b = (const float*)d_in[15];
    const float* gn_ms= (const float*)d_in[16];
    const float* Wout = (const float*)d_in[17];
    const float* bout = (const float*)d_in[18];

    int N = in_sizes[0];
    int E = in_sizes[1]/2;
    int OUT = out_size / NGRAPH;
    const int* srcp = eidx;
    const int* dstp = eidx + E;
    int nbuck = (N+63)>>6;

    char* w = (char*)d_ws;
    auto alloc = [&](size_t bytes) -> void* {
        void* p = (void*)w; w += (bytes+255)&~(size_t)255; return p;
    };
    int zfloats   = 256 + 2*NGRAPH*EMB;
    float* zbuf   = (float*)alloc((size_t)zfloats*4);
    float* colsum = zbuf;
    float* colsq  = zbuf + 128;
    float* gsum   = zbuf + 256;
    float* gsq    = gsum + (size_t)NGRAPH*EMB;
    int* bcnt_part= (int*)alloc((size_t)NCNT*MAXBUCK*4);
    int* bbase    = (int*)alloc((MAXBUCK+1)*4);
    int* bcursor  = (int*)alloc(MAXBUCK*4);
    unsigned* ebuf= (unsigned*)alloc((size_t)E*4);
    unsigned short* csr16 = (unsigned short*)alloc((size_t)E*2);
    int* rowstart = (int*)alloc((size_t)(MAXBUCK*64+64)*4);
    float* c_sd   = (float*)alloc(256);
    float* s0     = (float*)alloc((size_t)N*4);
    int* gstart   = (int*)alloc((NGRAPH+1)*4);
    f16_t* Hbuf   = (f16_t*)alloc((size_t)N*EMB*2);
    unsigned char* h1 = (unsigned char*)alloc((size_t)N*EMB);
    f16_t* h2     = (f16_t*)alloc((size_t)N*EMB*2);
    float* a_sv   = (float*)alloc((size_t)N*4);
    float* a_dv   = (float*)alloc((size_t)N*4);
    f16_t* pooled = (f16_t*)alloc(NGRAPH*256*2);
    f16_t* w1t    = (f16_t*)alloc(128*128*2);
    f16_t* woutt  = (f16_t*)alloc((size_t)4352*256*2);

    int zfloat4 = zfloats/4;
    int miscgrid = 586 + (N+255)/256;
    k_misc<<<miscgrid,256,0,stream>>>(W0,as0,ad0,c_sd,W1,w1t,Wout,OUT,woutt,
                                      dstp,E,nbuck,bcnt_part,zbuf,zfloat4,batch,N,gstart);
    k_bscan<<<1,1024,0,stream>>>(bcnt_part,nbuck,bbase,bcursor);
    int nchunk = (E+CHUNK-1)/CHUNK;
    k_bscatter<<<nchunk,512,0,stream>>>(srcp,dstp,E,nbuck,bcursor,ebuf);
    k_gat0<<<nbuck,256,0,stream>>>(ebuf,bbase,x,c_sd,batch,W0,b0,N,s0,csr16,rowstart,
                                   gsum,gsq,colsum,colsq);
    k_H<<<NGRAPH,256,0,stream>>>(s0,gstart,gsum,gsq,colsum,colsq,
                                 bn_g,bn_b,gn_w,gn_b,gn_ms,W0,b0,N,Hbuf);
    k_gemm1<<<(N+63)/64,256,0,stream>>>(Hbuf,w1t,as1,ad1,N,h1,a_sv,a_dv);
    k_gat1<<<(N+3)/4,256,0,stream>>>(csr16,rowstart,h1,a_sv,a_dv,b1,N,h2);
    k_pool<<<NGRAPH,64,0,stream>>>(h2,gstart,pooled);
    dim3 og(68, 8);
    k_out<<<og,256,0,stream>>>(pooled,woutt,bout,OUT,(float*)d_out);
}